// Round 2
// baseline (606.782 us; speedup 1.0000x reference)
//
#include <hip/hip_runtime.h>
#include <cstdint>

// Problem constants (fixed by reference)
#define N_TOK 16384
#define HDIM 1024
#define DEXP 512
#define NEXPERTS 8
#define VOCABM1 50256
#define BM 128
#define BN 128
#define BK 32
#define MAX_TILES 136          // 16384/128 + 8 (worst-case padding)
#define MPAD (MAX_TILES * BM)  // 17408

typedef __attribute__((ext_vector_type(8))) __bf16 bf16x8;
typedef __attribute__((ext_vector_type(4))) __bf16 bf16x4;
typedef __attribute__((ext_vector_type(4))) float f32x4;

__device__ inline void gl_lds16(const void* g, void* l) {
  __builtin_amdgcn_global_load_lds(
      (const __attribute__((address_space(1))) void*)g,
      (__attribute__((address_space(3))) void*)l, 16, 0, 0);
}

__device__ inline int expert_of(int t) {
  t = t < 0 ? 0 : (t > VOCABM1 ? VOCABM1 : t);
  return t & 7;
}

// ---------------- prep kernels ----------------
__global__ void k_count(const int* __restrict__ tok, int* __restrict__ counts) {
  int i = blockIdx.x * blockDim.x + threadIdx.x;
  if (i < N_TOK) atomicAdd(&counts[expert_of(tok[i])], 1);
}

__global__ void k_scan(const int* __restrict__ counts, int* __restrict__ paddedOff,
                       int* __restrict__ tileExpert, int* __restrict__ numTiles) {
  if (threadIdx.x == 0 && blockIdx.x == 0) {
    int t = 0;
    for (int e = 0; e < NEXPERTS; ++e) {
      paddedOff[e] = t * BM;
      int nt = (counts[e] + BM - 1) / BM;
      for (int i = 0; i < nt; ++i) tileExpert[t++] = e;
    }
    *numTiles = t;
  }
}

__global__ void k_scatter(const int* __restrict__ tok, const int* __restrict__ paddedOff,
                          int* __restrict__ cursor, int* __restrict__ perm) {
  int i = blockIdx.x * blockDim.x + threadIdx.x;
  if (i < N_TOK) {
    int e = expert_of(tok[i]);
    int pos = atomicAdd(&cursor[e], 1);
    perm[paddedOff[e] + pos] = i;
  }
}

// ---------------- conversions ----------------
__global__ void k_conv(const float* __restrict__ src, __bf16* __restrict__ dst, int n) {
  int i = (blockIdx.x * blockDim.x + threadIdx.x) * 4;
  if (i < n) {
    float4 v = *(const float4*)(src + i);
    bf16x4 o = {(__bf16)v.x, (__bf16)v.y, (__bf16)v.z, (__bf16)v.w};
    *(bf16x4*)(dst + i) = o;
  }
}

// src: [K][N] fp32 row-major -> dst: [rowmap(n)][K] bf16 (B^T layout).
// interleave: gate/up 16-col interleave, slot selects gate(0)/up(1) half.
__global__ void k_transpose(const float* __restrict__ src, __bf16* __restrict__ dst,
                            int K, int N, long srcStride, long dstStride,
                            int interleave, int slot) {
  __shared__ float tile[32][33];
  long sOff = (long)blockIdx.z * srcStride;
  long dOff = (long)blockIdx.z * dstStride;
  int n0 = blockIdx.x * 32, k0 = blockIdx.y * 32;
  // tile[p][q] = src[k0+p][n0+q]
  for (int kk = threadIdx.y; kk < 32; kk += 8)
    tile[kk][threadIdx.x] = src[sOff + (long)(k0 + kk) * N + n0 + threadIdx.x];
  __syncthreads();
  for (int nn = threadIdx.y; nn < 32; nn += 8) {
    int n = n0 + nn, k = k0 + threadIdx.x;
    int row = interleave ? (((n >> 4) << 5) | (slot << 4) | (n & 15)) : n;
    // FIX (R1): need element (k=k0+tx, n=n0+nn) = tile[tx][nn], NOT tile[nn][tx]
    dst[dOff + (long)row * K + k] = (__bf16)tile[threadIdx.x][nn];
  }
}

// ---------------- MFMA GEMM ----------------
// A: [rows][K] bf16 row-major.  B: [Ntot][K] bf16 (i.e. B^T, n-major rows).
// EPI 0: swiglu epilogue (gate/up 16-interleaved in N) -> outH bf16 [rows][ldh]
// EPI 1: plain fp32 store to outF [rows][1024]
// EPI 2: scatter: out[perm[row]] += acc (perm<0 rows skipped)
template <int EPI, bool GATHER_A, bool EXPERT_B>
__global__ __launch_bounds__(256) void k_gemm(
    const __bf16* __restrict__ A, const __bf16* __restrict__ B,
    float* __restrict__ outF, __bf16* __restrict__ outH,
    const int* __restrict__ perm, const int* __restrict__ tileExpert,
    const int* __restrict__ numTiles, int K, long bStride, int ldh) {
  int mTile = blockIdx.x, nTile = blockIdx.y;
  if (EXPERT_B) {
    if (mTile >= *numTiles) return;
  }
  const __bf16* Bb = B;
  if (EXPERT_B) Bb += (long)tileExpert[mTile] * bStride;

  __shared__ __bf16 As[BM * BK];
  __shared__ __bf16 Bs[BN * BK];

  int tid = threadIdx.x, lane = tid & 63, wave = tid >> 6;
  int wRow = (wave >> 1) * 64, wCol = (wave & 1) * 64;
  int mBase = mTile * BM;

  // staging: wave w covers rows [w*32, w*32+32); 4 lanes per row (8 bf16 each)
  int sRow = wave * 32 + (lane >> 2);
  int sCol = (lane & 3) * 8;
  long aRow0, aRow1;
  if (GATHER_A) {
    int t0 = perm[mBase + sRow];
    int t1 = perm[mBase + sRow + 16];
    aRow0 = t0 < 0 ? 0 : t0;
    aRow1 = t1 < 0 ? 0 : t1;
  } else {
    aRow0 = mBase + sRow;
    aRow1 = mBase + sRow + 16;
  }
  const __bf16* aP0 = A + aRow0 * (long)K + sCol;
  const __bf16* aP1 = A + aRow1 * (long)K + sCol;
  const __bf16* bP0 = Bb + ((long)nTile * BN + sRow) * K + sCol;
  const __bf16* bP1 = bP0 + 16L * K;
  __bf16* lA0 = &As[sRow * BK + sCol];
  __bf16* lA1 = &As[(sRow + 16) * BK + sCol];
  __bf16* lB0 = &Bs[sRow * BK + sCol];
  __bf16* lB1 = &Bs[(sRow + 16) * BK + sCol];

  f32x4 acc[4][4] = {};

  for (int k0 = 0; k0 < K; k0 += BK) {
    gl_lds16(aP0 + k0, lA0);
    gl_lds16(aP1 + k0, lA1);
    gl_lds16(bP0 + k0, lB0);
    gl_lds16(bP1 + k0, lB1);
    __syncthreads();
    bf16x8 af[4], bf[4];
#pragma unroll
    for (int i = 0; i < 4; ++i)
      af[i] = *(const bf16x8*)&As[(wRow + i * 16 + (lane & 15)) * BK + ((lane >> 4) * 8)];
#pragma unroll
    for (int j = 0; j < 4; ++j)
      bf[j] = *(const bf16x8*)&Bs[(wCol + j * 16 + (lane & 15)) * BK + ((lane >> 4) * 8)];
#pragma unroll
    for (int i = 0; i < 4; ++i)
#pragma unroll
      for (int j = 0; j < 4; ++j)
        acc[i][j] = __builtin_amdgcn_mfma_f32_16x16x32_bf16(af[i], bf[j], acc[i][j], 0, 0, 0);
    __syncthreads();
  }

  int q = lane >> 4;  // C/D: col = lane&15, row = q*4 + reg
  int c = lane & 15;
  if (EPI == 0) {
    int hColBase = nTile * 64 + (wCol >> 1);
#pragma unroll
    for (int i = 0; i < 4; ++i) {
      int rBase = mBase + wRow + i * 16 + q * 4;
#pragma unroll
      for (int jp = 0; jp < 2; ++jp) {
        f32x4 g = acc[i][2 * jp], u = acc[i][2 * jp + 1];
#pragma unroll
        for (int r = 0; r < 4; ++r) {
          float gv = g[r];
          float s = gv / (1.f + __expf(-gv)) * u[r];
          outH[(long)(rBase + r) * ldh + hColBase + jp * 16 + c] = (__bf16)s;
        }
      }
    }
  } else {
#pragma unroll
    for (int i = 0; i < 4; ++i) {
      int rowLoc = wRow + i * 16 + q * 4;
#pragma unroll
      for (int r = 0; r < 4; ++r) {
        long orow;
        bool ok = true;
        if (EPI == 2) {
          int tokv = perm[mBase + rowLoc + r];
          ok = tokv >= 0;
          orow = tokv;
        } else {
          orow = mBase + rowLoc + r;
        }
        if (ok) {
          float* op = outF + orow * 1024 + nTile * BN + wCol + c;
#pragma unroll
          for (int j = 0; j < 4; ++j) {
            float v = acc[i][j][r];
            if (EPI == 2)
              op[j * 16] += v;
            else
              op[j * 16] = v;
          }
        }
      }
    }
  }
}

// ---------------- launch ----------------
extern "C" void kernel_launch(void* const* d_in, const int* in_sizes, int n_in,
                              void* d_out, int out_size, void* d_ws, size_t ws_size,
                              hipStream_t stream) {
  const float* x = (const float*)d_in[0];
  const int* tok = (const int*)d_in[1];
  const float* gate_w = (const float*)d_in[2];
  const float* up_w = (const float*)d_in[3];
  const float* down_w = (const float*)d_in[4];
  const float* sgw = (const float*)d_in[5];
  const float* suw = (const float*)d_in[6];
  const float* sdw = (const float*)d_in[7];
  float* out = (float*)d_out;

  char* ws = (char*)d_ws;
  size_t off = 0;
  auto alloc = [&](size_t bytes) {
    void* p = ws + off;
    off = (off + bytes + 255) & ~(size_t)255;
    return p;
  };
  int* ctrl = (int*)alloc(1024);  // counts[8] cursor[8] paddedOff[8] numTiles[1] tileExpert[136]
  int* counts = ctrl;
  int* cursor = ctrl + 8;
  int* paddedOff = ctrl + 16;
  int* numTiles = ctrl + 24;
  int* tileExpert = ctrl + 32;
  int* perm = (int*)alloc((size_t)MPAD * 4);
  __bf16* xb = (__bf16*)alloc((size_t)N_TOK * HDIM * 2);
  __bf16* B1r = (__bf16*)alloc((size_t)NEXPERTS * 1024 * 1024 * 2);  // gate|up interleaved, transposed
  __bf16* B2r = (__bf16*)alloc((size_t)NEXPERTS * 1024 * 512 * 2);   // down transposed [n=1024][k=512]
  __bf16* B1s = (__bf16*)alloc((size_t)2048 * 1024 * 2);
  __bf16* B2s = (__bf16*)alloc((size_t)1024 * 1024 * 2);
  __bf16* hr = (__bf16*)alloc((size_t)MPAD * 512 * 2);
  __bf16* hs = (__bf16*)alloc((size_t)N_TOK * 1024 * 2);
  (void)ws_size;  // ~111 MB used

  hipMemsetAsync(ctrl, 0, 64, stream);                      // counts + cursor
  hipMemsetAsync(perm, 0xFF, (size_t)MPAD * 4, stream);     // -1 padding

  k_count<<<N_TOK / 256, 256, 0, stream>>>(tok, counts);
  k_scan<<<1, 64, 0, stream>>>(counts, paddedOff, tileExpert, numTiles);
  k_scatter<<<N_TOK / 256, 256, 0, stream>>>(tok, paddedOff, cursor, perm);

  k_conv<<<(N_TOK * HDIM / 4) / 256, 256, 0, stream>>>(x, xb, N_TOK * HDIM);

  // weights -> bf16 B^T layouts
  k_transpose<<<dim3(16, 32, 8), dim3(32, 8), 0, stream>>>(gate_w, B1r, 1024, 512, 1024L * 512, 1024L * 1024, 1, 0);
  k_transpose<<<dim3(16, 32, 8), dim3(32, 8), 0, stream>>>(up_w, B1r, 1024, 512, 1024L * 512, 1024L * 1024, 1, 1);
  k_transpose<<<dim3(32, 16, 8), dim3(32, 8), 0, stream>>>(down_w, B2r, 512, 1024, 512L * 1024, 1024L * 512, 0, 0);
  k_transpose<<<dim3(32, 32, 1), dim3(32, 8), 0, stream>>>(sgw, B1s, 1024, 1024, 0, 0, 1, 0);
  k_transpose<<<dim3(32, 32, 1), dim3(32, 8), 0, stream>>>(suw, B1s, 1024, 1024, 0, 0, 1, 1);
  k_transpose<<<dim3(32, 32, 1), dim3(32, 8), 0, stream>>>(sdw, B2s, 1024, 1024, 0, 0, 0, 0);

  // shared up-proj + swiglu -> hs [16384][1024]
  k_gemm<0, false, false><<<dim3(128, 16), 256, 0, stream>>>(
      xb, B1s, nullptr, hs, nullptr, nullptr, nullptr, 1024, 0, 1024);
  // routed up-proj (gathered) + swiglu -> hr [MPAD][512]
  k_gemm<0, true, true><<<dim3(MAX_TILES, 8), 256, 0, stream>>>(
      xb, B1r, nullptr, hr, perm, tileExpert, numTiles, 1024, 1024L * 1024, 512);
  // shared down-proj -> out (store)
  k_gemm<1, false, false><<<dim3(128, 8), 256, 0, stream>>>(
      hs, B2s, out, nullptr, nullptr, nullptr, nullptr, 1024, 0, 0);
  // routed down-proj -> out (scatter +=)
  k_gemm<2, false, true><<<dim3(MAX_TILES, 8), 256, 0, stream>>>(
      hr, B2r, out, nullptr, perm, tileExpert, numTiles, 512, 1024L * 512, 0);
}

// Round 3
// 575.959 us; speedup vs baseline: 1.0535x; 1.0535x over previous
//
#include <hip/hip_runtime.h>
#include <cstdint>

#define N_TOK 16384
#define HDIM 1024
#define NEXPERTS 8
#define VOCABM1 50256
#define BM 128
#define BN 128
#define BK 32
#define MAX_TILES 136          // 16384/128 + 8 (worst-case padding)
#define MPAD (MAX_TILES * BM)  // 17408

typedef __attribute__((ext_vector_type(8))) __bf16 bf16x8;
typedef __attribute__((ext_vector_type(4))) __bf16 bf16x4;
typedef __attribute__((ext_vector_type(2))) __bf16 bf16x2;
typedef __attribute__((ext_vector_type(4))) float f32x4;

__device__ inline void gl_lds16(const void* g, void* l) {
  __builtin_amdgcn_global_load_lds(
      (const __attribute__((address_space(1))) void*)g,
      (__attribute__((address_space(3))) void*)l, 16, 0, 0);
}

__device__ inline int expert_of(int t) {
  t = t < 0 ? 0 : (t > VOCABM1 ? VOCABM1 : t);
  return t & 7;
}

// ---------------- prep kernels ----------------
__global__ void k_count(const int* __restrict__ tok, int* __restrict__ counts) {
  int i = blockIdx.x * blockDim.x + threadIdx.x;
  if (i < N_TOK) atomicAdd(&counts[expert_of(tok[i])], 1);
}

__global__ void k_scan(const int* __restrict__ counts, int* __restrict__ paddedOff,
                       int* __restrict__ tileExpert, int* __restrict__ numTiles) {
  if (threadIdx.x == 0 && blockIdx.x == 0) {
    int t = 0;
    for (int e = 0; e < NEXPERTS; ++e) {
      paddedOff[e] = t * BM;
      int nt = (counts[e] + BM - 1) / BM;
      for (int i = 0; i < nt; ++i) tileExpert[t++] = e;
    }
    *numTiles = t;
  }
}

__global__ void k_scatter(const int* __restrict__ tok, const int* __restrict__ paddedOff,
                          int* __restrict__ cursor, int* __restrict__ perm) {
  int i = blockIdx.x * blockDim.x + threadIdx.x;
  if (i < N_TOK) {
    int e = expert_of(tok[i]);
    int pos = atomicAdd(&cursor[e], 1);
    perm[paddedOff[e] + pos] = i;
  }
}

// ---------------- fused gather + fp32->bf16 convert: xp[p] = bf16(x[perm[p]]) ----------------
__global__ void k_convperm(const float* __restrict__ x, const int* __restrict__ perm,
                           __bf16* __restrict__ xp) {
  int tid = threadIdx.x;
  int p = blockIdx.x * 4 + (tid >> 6);
  int t = perm[p];
  __bf16* dst = xp + (long)p * HDIM;
  int c0 = (tid & 63) * 4;
  if (t < 0) {
    bf16x4 z = {};
#pragma unroll
    for (int it = 0; it < 4; ++it) *(bf16x4*)(dst + c0 + it * 256) = z;
  } else {
    const float* src = x + (long)t * HDIM;
#pragma unroll
    for (int it = 0; it < 4; ++it) {
      float4 v = *(const float4*)(src + c0 + it * 256);
      bf16x4 o = {(__bf16)v.x, (__bf16)v.y, (__bf16)v.z, (__bf16)v.w};
      *(bf16x4*)(dst + c0 + it * 256) = o;
    }
  }
}

// ---------------- 64x64 transpose+convert: src [K][N] fp32 -> dst [rowmap(n)][K] bf16 ----------------
// blockIdx.z: slot = z / nz0 (selects src0/src1 and interleave half), e = z % nz0.
__global__ void k_trans64(const float* __restrict__ src0, const float* __restrict__ src1,
                          __bf16* __restrict__ dst, int K, int N,
                          long dstEStride, int nz0, int interleave) {
  __shared__ float tile[64][65];
  int z = blockIdx.z;
  int slot = z / nz0;
  int e = z % nz0;
  const float* src = (slot ? src1 : src0) + (long)e * K * N;
  __bf16* dstp = dst + (long)e * dstEStride;
  int n0 = blockIdx.x * 64, k0 = blockIdx.y * 64;
  int tid = threadIdx.x;
  int tx = tid & 15, ty = tid >> 4;
#pragma unroll
  for (int rr = 0; rr < 64; rr += 16) {
    float4 v = *(const float4*)(src + (long)(k0 + ty + rr) * N + n0 + tx * 4);
    tile[ty + rr][tx * 4 + 0] = v.x;
    tile[ty + rr][tx * 4 + 1] = v.y;
    tile[ty + rr][tx * 4 + 2] = v.z;
    tile[ty + rr][tx * 4 + 3] = v.w;
  }
  __syncthreads();
  int kp = tid & 31, rs = tid >> 5;
#pragma unroll
  for (int rr = 0; rr < 64; rr += 8) {
    int n = n0 + rs + rr;
    int row = interleave ? (((n >> 4) << 5) | (slot << 4) | (n & 15)) : n;
    bf16x2 u = {(__bf16)tile[2 * kp][rs + rr], (__bf16)tile[2 * kp + 1][rs + rr]};
    *(bf16x2*)(dstp + (long)row * K + k0 + 2 * kp) = u;
  }
}

// ---------------- fused up-projection GEMM (shared + routed) ----------------
// A = xp [MPAD][1024]. ny<16: B=B1s (shared, 2048 rows), out hs_p; ny>=16: B=B1r[e], out hr.
// LDS XOR chunk swizzle (R3): staging lane L fetches global 16B-chunk (L&3)^((L>>3)&3);
// fragment reads use chunk q^((lane>>1)&3) -> 16 fragment rows spread over all 8
// chunk-slots (2-way, free) instead of 8-way conflicts.
__global__ __launch_bounds__(256) void k_up(
    const __bf16* __restrict__ A, const __bf16* __restrict__ B1s,
    const __bf16* __restrict__ B1r, __bf16* __restrict__ hs, __bf16* __restrict__ hr,
    const int* __restrict__ tileExpert, const int* __restrict__ numTiles) {
  int mTile = blockIdx.x, ny = blockIdx.y;
  if (mTile >= *numTiles) return;
  bool sh = (ny < 16);
  const __bf16* Bb = sh ? (B1s + (long)ny * BN * 1024)
                        : (B1r + (long)tileExpert[mTile] * (1024L * 1024) +
                           (long)(ny - 16) * BN * 1024);

  __shared__ __bf16 As[BM * BK];
  __shared__ __bf16 Bs[BN * BK];

  int tid = threadIdx.x, lane = tid & 63, wave = tid >> 6;
  int wRow = (wave >> 1) * 64, wCol = (wave & 1) * 64;
  int mBase = mTile * BM;

  int rloc = lane >> 2;
  int cg = ((lane & 3) ^ ((lane >> 3) & 3)) * 8;  // swizzled global chunk (elements)
  const __bf16* aP0 = A + (long)(mBase + wave * 32 + rloc) * 1024 + cg;
  const __bf16* aP1 = aP0 + 16 * 1024;
  const __bf16* bP0 = Bb + (long)(wave * 32 + rloc) * 1024 + cg;
  const __bf16* bP1 = bP0 + 16 * 1024;
  __bf16* lA0 = &As[(wave * 32) * BK];
  __bf16* lA1 = &As[(wave * 32 + 16) * BK];
  __bf16* lB0 = &Bs[(wave * 32) * BK];
  __bf16* lB1 = &Bs[(wave * 32 + 16) * BK];

  int m = lane & 15;
  int qs = ((lane >> 4) ^ ((lane >> 1) & 3)) * 8;  // swizzled read chunk (elements)
  const int aBase = (wRow + m) * BK + qs;
  const int bBase = (wCol + m) * BK + qs;

  f32x4 acc[4][4] = {};
  for (int k0 = 0; k0 < 1024; k0 += BK) {
    gl_lds16(aP0 + k0, lA0);
    gl_lds16(aP1 + k0, lA1);
    gl_lds16(bP0 + k0, lB0);
    gl_lds16(bP1 + k0, lB1);
    __syncthreads();
    bf16x8 af[4], bf[4];
#pragma unroll
    for (int i = 0; i < 4; ++i) af[i] = *(const bf16x8*)&As[aBase + i * 16 * BK];
#pragma unroll
    for (int j = 0; j < 4; ++j) bf[j] = *(const bf16x8*)&Bs[bBase + j * 16 * BK];
#pragma unroll
    for (int i = 0; i < 4; ++i)
#pragma unroll
      for (int j = 0; j < 4; ++j)
        acc[i][j] = __builtin_amdgcn_mfma_f32_16x16x32_bf16(af[i], bf[j], acc[i][j], 0, 0, 0);
    __syncthreads();
  }

  int q = lane >> 4, c = lane & 15;  // C/D: col = lane&15, row = q*4 + reg
  __bf16* dst = sh ? hs : hr;
  int ldh = sh ? 1024 : 512;
  int hColBase = (sh ? ny * 64 : (ny - 16) * 64) + (wCol >> 1);
#pragma unroll
  for (int i = 0; i < 4; ++i) {
    int rBase = mBase + wRow + i * 16 + q * 4;
#pragma unroll
    for (int jp = 0; jp < 2; ++jp) {
      f32x4 g = acc[i][2 * jp], u = acc[i][2 * jp + 1];
#pragma unroll
      for (int r = 0; r < 4; ++r) {
        float gv = g[r];
        float s = gv / (1.f + __expf(-gv)) * u[r];
        dst[(long)(rBase + r) * ldh + hColBase + jp * 16 + c] = (__bf16)s;
      }
    }
  }
}

// ---------------- fused down-projection GEMM: out[perm[p]] = hs_p[p]*B2s + hr[p]*B2r[e] ----------------
__global__ __launch_bounds__(256) void k_down(
    const __bf16* __restrict__ hs, const __bf16* __restrict__ hr,
    const __bf16* __restrict__ B2s, const __bf16* __restrict__ B2r,
    float* __restrict__ out, const int* __restrict__ perm,
    const int* __restrict__ tileExpert, const int* __restrict__ numTiles) {
  int mTile = blockIdx.x, nTile = blockIdx.y;
  if (mTile >= *numTiles) return;
  int e = tileExpert[mTile];

  __shared__ __bf16 As[BM * BK];
  __shared__ __bf16 Bs[BN * BK];

  int tid = threadIdx.x, lane = tid & 63, wave = tid >> 6;
  int wRow = (wave >> 1) * 64, wCol = (wave & 1) * 64;
  int mBase = mTile * BM;

  int rloc = lane >> 2;
  int cg = ((lane & 3) ^ ((lane >> 3) & 3)) * 8;
  __bf16* lA0 = &As[(wave * 32) * BK];
  __bf16* lA1 = &As[(wave * 32 + 16) * BK];
  __bf16* lB0 = &Bs[(wave * 32) * BK];
  __bf16* lB1 = &Bs[(wave * 32 + 16) * BK];

  int m = lane & 15;
  int qs = ((lane >> 4) ^ ((lane >> 1) & 3)) * 8;
  const int aBase = (wRow + m) * BK + qs;
  const int bBase = (wCol + m) * BK + qs;

  f32x4 acc[4][4] = {};

  // phase 1: shared down (K=1024)
  {
    const __bf16* aP0 = hs + (long)(mBase + wave * 32 + rloc) * 1024 + cg;
    const __bf16* aP1 = aP0 + 16 * 1024;
    const __bf16* bP0 = B2s + (long)(nTile * BN + wave * 32 + rloc) * 1024 + cg;
    const __bf16* bP1 = bP0 + 16 * 1024;
    for (int k0 = 0; k0 < 1024; k0 += BK) {
      gl_lds16(aP0 + k0, lA0);
      gl_lds16(aP1 + k0, lA1);
      gl_lds16(bP0 + k0, lB0);
      gl_lds16(bP1 + k0, lB1);
      __syncthreads();
      bf16x8 af[4], bf[4];
#pragma unroll
      for (int i = 0; i < 4; ++i) af[i] = *(const bf16x8*)&As[aBase + i * 16 * BK];
#pragma unroll
      for (int j = 0; j < 4; ++j) bf[j] = *(const bf16x8*)&Bs[bBase + j * 16 * BK];
#pragma unroll
      for (int i = 0; i < 4; ++i)
#pragma unroll
        for (int j = 0; j < 4; ++j)
          acc[i][j] = __builtin_amdgcn_mfma_f32_16x16x32_bf16(af[i], bf[j], acc[i][j], 0, 0, 0);
      __syncthreads();
    }
  }
  // phase 2: routed down (K=512)
  {
    const __bf16* aP0 = hr + (long)(mBase + wave * 32 + rloc) * 512 + cg;
    const __bf16* aP1 = aP0 + 16 * 512;
    const __bf16* bP0 = B2r + (long)e * (1024L * 512) +
                        (long)(nTile * BN + wave * 32 + rloc) * 512 + cg;
    const __bf16* bP1 = bP0 + 16 * 512;
    for (int k0 = 0; k0 < 512; k0 += BK) {
      gl_lds16(aP0 + k0, lA0);
      gl_lds16(aP1 + k0, lA1);
      gl_lds16(bP0 + k0, lB0);
      gl_lds16(bP1 + k0, lB1);
      __syncthreads();
      bf16x8 af[4], bf[4];
#pragma unroll
      for (int i = 0; i < 4; ++i) af[i] = *(const bf16x8*)&As[aBase + i * 16 * BK];
#pragma unroll
      for (int j = 0; j < 4; ++j) bf[j] = *(const bf16x8*)&Bs[bBase + j * 16 * BK];
#pragma unroll
      for (int i = 0; i < 4; ++i)
#pragma unroll
        for (int j = 0; j < 4; ++j)
          acc[i][j] = __builtin_amdgcn_mfma_f32_16x16x32_bf16(af[i], bf[j], acc[i][j], 0, 0, 0);
      __syncthreads();
    }
  }

  int q = lane >> 4, c = lane & 15;
#pragma unroll
  for (int i = 0; i < 4; ++i) {
    int rowLoc = wRow + i * 16 + q * 4;
#pragma unroll
    for (int r = 0; r < 4; ++r) {
      int tok = perm[mBase + rowLoc + r];
      if (tok >= 0) {
        float* op = out + (long)tok * 1024 + nTile * BN + wCol + c;
#pragma unroll
        for (int j = 0; j < 4; ++j) op[j * 16] = acc[i][j][r];
      }
    }
  }
}

// ---------------- launch ----------------
extern "C" void kernel_launch(void* const* d_in, const int* in_sizes, int n_in,
                              void* d_out, int out_size, void* d_ws, size_t ws_size,
                              hipStream_t stream) {
  const float* x = (const float*)d_in[0];
  const int* tok = (const int*)d_in[1];
  const float* gate_w = (const float*)d_in[2];
  const float* up_w = (const float*)d_in[3];
  const float* down_w = (const float*)d_in[4];
  const float* sgw = (const float*)d_in[5];
  const float* suw = (const float*)d_in[6];
  const float* sdw = (const float*)d_in[7];
  float* out = (float*)d_out;

  char* ws = (char*)d_ws;
  size_t off = 0;
  auto alloc = [&](size_t bytes) {
    void* p = ws + off;
    off = (off + bytes + 255) & ~(size_t)255;
    return p;
  };
  int* ctrl = (int*)alloc(1024);  // counts[8] cursor[8] paddedOff[8] numTiles[1] tileExpert[136]
  int* counts = ctrl;
  int* cursor = ctrl + 8;
  int* paddedOff = ctrl + 16;
  int* numTiles = ctrl + 24;
  int* tileExpert = ctrl + 32;
  int* perm = (int*)alloc((size_t)MPAD * 4);
  __bf16* xp = (__bf16*)alloc((size_t)MPAD * HDIM * 2);
  __bf16* B1r = (__bf16*)alloc((size_t)NEXPERTS * 1024 * 1024 * 2);  // gate|up interleaved
  __bf16* B2r = (__bf16*)alloc((size_t)NEXPERTS * 1024 * 512 * 2);
  __bf16* B1s = (__bf16*)alloc((size_t)2048 * 1024 * 2);
  __bf16* B2s = (__bf16*)alloc((size_t)1024 * 1024 * 2);
  __bf16* hs = (__bf16*)alloc((size_t)MPAD * 1024 * 2);
  __bf16* hr = (__bf16*)alloc((size_t)MPAD * 512 * 2);
  (void)ws_size;  // ~121 MB used

  hipMemsetAsync(ctrl, 0, 64, stream);                   // counts + cursor
  hipMemsetAsync(perm, 0xFF, (size_t)MPAD * 4, stream);  // -1 padding

  k_count<<<N_TOK / 256, 256, 0, stream>>>(tok, counts);
  k_scan<<<1, 64, 0, stream>>>(counts, paddedOff, tileExpert, numTiles);
  k_scatter<<<N_TOK / 256, 256, 0, stream>>>(tok, paddedOff, cursor, perm);
  k_convperm<<<MPAD / 4, 256, 0, stream>>>(x, perm, xp);

  // weights -> bf16 B^T layouts (64x64 tiles, fused pairs)
  k_trans64<<<dim3(8, 16, 16), 256, 0, stream>>>(gate_w, up_w, B1r, 1024, 512,
                                                 1024L * 1024, 8, 1);
  k_trans64<<<dim3(16, 8, 8), 256, 0, stream>>>(down_w, nullptr, B2r, 512, 1024,
                                                1024L * 512, 8, 0);
  k_trans64<<<dim3(16, 16, 2), 256, 0, stream>>>(sgw, suw, B1s, 1024, 1024, 0, 1, 1);
  k_trans64<<<dim3(16, 16, 1), 256, 0, stream>>>(sdw, nullptr, B2s, 1024, 1024, 0, 1, 0);

  // fused up-projection (shared n-tiles 0..15, routed 16..23) + swiglu
  k_up<<<dim3(MAX_TILES, 24), 256, 0, stream>>>(xp, B1s, B1r, hs, hr, tileExpert, numTiles);
  // fused down-projection (K=1024 shared + K=512 routed) + scatter store
  k_down<<<dim3(MAX_TILES, 8), 256, 0, stream>>>(hs, hr, B2s, B2r, out, perm, tileExpert,
                                                 numTiles);
}

// Round 4
// 448.031 us; speedup vs baseline: 1.3543x; 1.2855x over previous
//
#include <hip/hip_runtime.h>
#include <cstdint>

#define N_TOK 16384
#define HDIM 1024
#define NEXPERTS 8
#define VOCABM1 50256
#define BM 128
#define BN 128
#define BK 32
#define MAX_TILES 136          // 16384/128 + 8 (worst-case padding)
#define MPAD (MAX_TILES * BM)  // 17408

typedef __attribute__((ext_vector_type(8))) __bf16 bf16x8;
typedef __attribute__((ext_vector_type(4))) __bf16 bf16x4;
typedef __attribute__((ext_vector_type(2))) __bf16 bf16x2;
typedef __attribute__((ext_vector_type(4))) float f32x4;

__device__ inline void gl_lds16(const void* g, void* l) {
  __builtin_amdgcn_global_load_lds(
      (const __attribute__((address_space(1))) void*)g,
      (__attribute__((address_space(3))) void*)l, 16, 0, 0);
}

__device__ inline int expert_of(int t) {
  t = t < 0 ? 0 : (t > VOCABM1 ? VOCABM1 : t);
  return t & 7;
}

// ---------------- fused routing: histogram + tile table + padded permutation ----------------
// Single block, 1024 threads. Replaces k_count/k_scan/k_scatter + 2 memsets (R4):
// those kernels did 2x16384 device-scope atomicAdd onto 8 addresses (lane-varying
// target -> no wave coalescing -> ~2048 serialized RMWs per address).
__global__ __launch_bounds__(1024) void k_route(const int* __restrict__ tok,
                                                int* __restrict__ perm,
                                                int* __restrict__ tileExpert,
                                                int* __restrict__ numTiles) {
  __shared__ int cnt[NEXPERTS];
  __shared__ int cur[NEXPERTS];
  int tid = threadIdx.x;
  if (tid < NEXPERTS) cnt[tid] = 0;
  __syncthreads();

  int base = tid * 16;
  int4 v[4];
  const int4* t4 = (const int4*)(tok + base);
#pragma unroll
  for (int i = 0; i < 4; ++i) v[i] = t4[i];
  int myE[16];
  int loc[NEXPERTS];
#pragma unroll
  for (int e = 0; e < NEXPERTS; ++e) loc[e] = 0;
#pragma unroll
  for (int i = 0; i < 16; ++i) {
    int e = expert_of(((const int*)v)[i]);
    myE[i] = e;
    ++loc[e];
  }
#pragma unroll
  for (int e = 0; e < NEXPERTS; ++e)
    if (loc[e]) atomicAdd(&cnt[e], loc[e]);
  __syncthreads();

  if (tid == 0) {
    int t = 0;
    for (int e = 0; e < NEXPERTS; ++e) {
      cur[e] = t * BM;  // padded offset doubles as scatter cursor
      int nt = (cnt[e] + BM - 1) / BM;
      for (int i = 0; i < nt; ++i) tileExpert[t++] = e;
    }
    *numTiles = t;
  }
  __syncthreads();

  for (int i = tid; i < MPAD; i += 1024) perm[i] = -1;
  __syncthreads();

#pragma unroll
  for (int i = 0; i < 16; ++i) {
    int pos = atomicAdd(&cur[myE[i]], 1);
    perm[pos] = base + i;
  }
}

// ---------------- fused gather + fp32->bf16 convert: xp[p] = bf16(x[perm[p]]) ----------------
__global__ void k_convperm(const float* __restrict__ x, const int* __restrict__ perm,
                           __bf16* __restrict__ xp) {
  int tid = threadIdx.x;
  int p = blockIdx.x * 4 + (tid >> 6);
  int t = perm[p];
  __bf16* dst = xp + (long)p * HDIM;
  int c0 = (tid & 63) * 4;
  if (t < 0) {
    bf16x4 z = {};
#pragma unroll
    for (int it = 0; it < 4; ++it) *(bf16x4*)(dst + c0 + it * 256) = z;
  } else {
    const float* src = x + (long)t * HDIM;
#pragma unroll
    for (int it = 0; it < 4; ++it) {
      float4 v = *(const float4*)(src + c0 + it * 256);
      bf16x4 o = {(__bf16)v.x, (__bf16)v.y, (__bf16)v.z, (__bf16)v.w};
      *(bf16x4*)(dst + c0 + it * 256) = o;
    }
  }
}

// ---------------- merged weight transpose+convert (all 6 matrices, one dispatch) ----------------
// 64x64 tiles; flat block id decodes the job. src [K][N] fp32 -> dst [rowmap(n)][K] bf16.
__global__ void k_trans(const float* __restrict__ gw, const float* __restrict__ uw,
                        const float* __restrict__ dw, const float* __restrict__ sgw,
                        const float* __restrict__ suw, const float* __restrict__ sdw,
                        __bf16* __restrict__ B1r, __bf16* __restrict__ B2r,
                        __bf16* __restrict__ B1s, __bf16* __restrict__ B2s) {
  int b = blockIdx.x;
  const float* src;
  __bf16* dst;
  int K, N, interleave, slot, xt, yt;
  if (b < 2048) {  // gate_w/up_w -> B1r (16-col gate/up interleave)
    slot = b >> 10;
    int r = b & 1023, e = r >> 7, t = r & 127;
    xt = t & 7; yt = t >> 3;
    K = 1024; N = 512; interleave = 1;
    src = (slot ? uw : gw) + (long)e * (1024L * 512);
    dst = B1r + (long)e * (1024L * 1024);
  } else if (b < 3072) {  // down_w -> B2r
    int r = b - 2048, e = r >> 7, t = r & 127;
    xt = t & 15; yt = t >> 4;
    K = 512; N = 1024; interleave = 0; slot = 0;
    src = dw + (long)e * (512L * 1024);
    dst = B2r + (long)e * (1024L * 512);
  } else if (b < 3584) {  // shared gate/up -> B1s
    int r = b - 3072;
    slot = r >> 8;
    int t = r & 255;
    xt = t & 15; yt = t >> 4;
    K = 1024; N = 1024; interleave = 1;
    src = slot ? suw : sgw;
    dst = B1s;
  } else {  // shared down -> B2s
    int t = b - 3584;
    xt = t & 15; yt = t >> 4;
    K = 1024; N = 1024; interleave = 0; slot = 0;
    src = sdw;
    dst = B2s;
  }

  __shared__ float tile[64][65];
  int n0 = xt * 64, k0 = yt * 64;
  int tid = threadIdx.x, tx = tid & 15, ty = tid >> 4;
#pragma unroll
  for (int rr = 0; rr < 64; rr += 16) {
    float4 v = *(const float4*)(src + (long)(k0 + ty + rr) * N + n0 + tx * 4);
    tile[ty + rr][tx * 4 + 0] = v.x;
    tile[ty + rr][tx * 4 + 1] = v.y;
    tile[ty + rr][tx * 4 + 2] = v.z;
    tile[ty + rr][tx * 4 + 3] = v.w;
  }
  __syncthreads();
  int kp = tid & 31, rs = tid >> 5;
#pragma unroll
  for (int rr = 0; rr < 64; rr += 8) {
    int n = n0 + rs + rr;
    int row = interleave ? (((n >> 4) << 5) | (slot << 4) | (n & 15)) : n;
    bf16x2 u = {(__bf16)tile[2 * kp][rs + rr], (__bf16)tile[2 * kp + 1][rs + rr]};
    *(bf16x2*)(dst + (long)row * K + k0 + 2 * kp) = u;
  }
}

// ---------------- fused up-projection GEMM (shared + routed) ----------------
// A = xp [MPAD][1024]. ny<16: B=B1s (shared), out hs; ny>=16: B=B1r[e], out hr.
// LDS XOR chunk swizzle (R3): staging lane L fetches global 16B-chunk (L&3)^((L>>3)&3);
// fragment reads use chunk q^((lane>>1)&3) -> 2-way (free) instead of 8-way conflicts.
__global__ __launch_bounds__(256) void k_up(
    const __bf16* __restrict__ A, const __bf16* __restrict__ B1s,
    const __bf16* __restrict__ B1r, __bf16* __restrict__ hs, __bf16* __restrict__ hr,
    const int* __restrict__ tileExpert, const int* __restrict__ numTiles) {
  int mTile = blockIdx.x, ny = blockIdx.y;
  if (mTile >= *numTiles) return;
  bool sh = (ny < 16);
  const __bf16* Bb = sh ? (B1s + (long)ny * BN * 1024)
                        : (B1r + (long)tileExpert[mTile] * (1024L * 1024) +
                           (long)(ny - 16) * BN * 1024);

  __shared__ __bf16 As[BM * BK];
  __shared__ __bf16 Bs[BN * BK];

  int tid = threadIdx.x, lane = tid & 63, wave = tid >> 6;
  int wRow = (wave >> 1) * 64, wCol = (wave & 1) * 64;
  int mBase = mTile * BM;

  int rloc = lane >> 2;
  int cg = ((lane & 3) ^ ((lane >> 3) & 3)) * 8;  // swizzled global chunk (elements)
  const __bf16* aP0 = A + (long)(mBase + wave * 32 + rloc) * 1024 + cg;
  const __bf16* aP1 = aP0 + 16 * 1024;
  const __bf16* bP0 = Bb + (long)(wave * 32 + rloc) * 1024 + cg;
  const __bf16* bP1 = bP0 + 16 * 1024;
  __bf16* lA0 = &As[(wave * 32) * BK];
  __bf16* lA1 = &As[(wave * 32 + 16) * BK];
  __bf16* lB0 = &Bs[(wave * 32) * BK];
  __bf16* lB1 = &Bs[(wave * 32 + 16) * BK];

  int m = lane & 15;
  int qs = ((lane >> 4) ^ ((lane >> 1) & 3)) * 8;  // swizzled read chunk (elements)
  const int aBase = (wRow + m) * BK + qs;
  const int bBase = (wCol + m) * BK + qs;

  f32x4 acc[4][4] = {};
  for (int k0 = 0; k0 < 1024; k0 += BK) {
    gl_lds16(aP0 + k0, lA0);
    gl_lds16(aP1 + k0, lA1);
    gl_lds16(bP0 + k0, lB0);
    gl_lds16(bP1 + k0, lB1);
    __syncthreads();
    bf16x8 af[4], bf[4];
#pragma unroll
    for (int i = 0; i < 4; ++i) af[i] = *(const bf16x8*)&As[aBase + i * 16 * BK];
#pragma unroll
    for (int j = 0; j < 4; ++j) bf[j] = *(const bf16x8*)&Bs[bBase + j * 16 * BK];
#pragma unroll
    for (int i = 0; i < 4; ++i)
#pragma unroll
      for (int j = 0; j < 4; ++j)
        acc[i][j] = __builtin_amdgcn_mfma_f32_16x16x32_bf16(af[i], bf[j], acc[i][j], 0, 0, 0);
    __syncthreads();
  }

  int q = lane >> 4, c = lane & 15;  // C/D: col = lane&15, row = q*4 + reg
  __bf16* dst = sh ? hs : hr;
  int ldh = sh ? 1024 : 512;
  int hColBase = (sh ? ny * 64 : (ny - 16) * 64) + (wCol >> 1);
#pragma unroll
  for (int i = 0; i < 4; ++i) {
    int rBase = mBase + wRow + i * 16 + q * 4;
#pragma unroll
    for (int jp = 0; jp < 2; ++jp) {
      f32x4 g = acc[i][2 * jp], u = acc[i][2 * jp + 1];
#pragma unroll
      for (int r = 0; r < 4; ++r) {
        float gv = g[r];
        float s = gv / (1.f + __expf(-gv)) * u[r];
        dst[(long)(rBase + r) * ldh + hColBase + jp * 16 + c] = (__bf16)s;
      }
    }
  }
}

// ---------------- fused down-projection GEMM: out[perm[p]] = hs[p]*B2s + hr[p]*B2r[e] ----------------
__global__ __launch_bounds__(256) void k_down(
    const __bf16* __restrict__ hs, const __bf16* __restrict__ hr,
    const __bf16* __restrict__ B2s, const __bf16* __restrict__ B2r,
    float* __restrict__ out, const int* __restrict__ perm,
    const int* __restrict__ tileExpert, const int* __restrict__ numTiles) {
  int mTile = blockIdx.x, nTile = blockIdx.y;
  if (mTile >= *numTiles) return;
  int e = tileExpert[mTile];

  __shared__ __bf16 As[BM * BK];
  __shared__ __bf16 Bs[BN * BK];

  int tid = threadIdx.x, lane = tid & 63, wave = tid >> 6;
  int wRow = (wave >> 1) * 64, wCol = (wave & 1) * 64;
  int mBase = mTile * BM;

  int rloc = lane >> 2;
  int cg = ((lane & 3) ^ ((lane >> 3) & 3)) * 8;
  __bf16* lA0 = &As[(wave * 32) * BK];
  __bf16* lA1 = &As[(wave * 32 + 16) * BK];
  __bf16* lB0 = &Bs[(wave * 32) * BK];
  __bf16* lB1 = &Bs[(wave * 32 + 16) * BK];

  int m = lane & 15;
  int qs = ((lane >> 4) ^ ((lane >> 1) & 3)) * 8;
  const int aBase = (wRow + m) * BK + qs;
  const int bBase = (wCol + m) * BK + qs;

  f32x4 acc[4][4] = {};

  // phase 1: shared down (K=1024)
  {
    const __bf16* aP0 = hs + (long)(mBase + wave * 32 + rloc) * 1024 + cg;
    const __bf16* aP1 = aP0 + 16 * 1024;
    const __bf16* bP0 = B2s + (long)(nTile * BN + wave * 32 + rloc) * 1024 + cg;
    const __bf16* bP1 = bP0 + 16 * 1024;
    for (int k0 = 0; k0 < 1024; k0 += BK) {
      gl_lds16(aP0 + k0, lA0);
      gl_lds16(aP1 + k0, lA1);
      gl_lds16(bP0 + k0, lB0);
      gl_lds16(bP1 + k0, lB1);
      __syncthreads();
      bf16x8 af[4], bf[4];
#pragma unroll
      for (int i = 0; i < 4; ++i) af[i] = *(const bf16x8*)&As[aBase + i * 16 * BK];
#pragma unroll
      for (int j = 0; j < 4; ++j) bf[j] = *(const bf16x8*)&Bs[bBase + j * 16 * BK];
#pragma unroll
      for (int i = 0; i < 4; ++i)
#pragma unroll
        for (int j = 0; j < 4; ++j)
          acc[i][j] = __builtin_amdgcn_mfma_f32_16x16x32_bf16(af[i], bf[j], acc[i][j], 0, 0, 0);
      __syncthreads();
    }
  }
  // phase 2: routed down (K=512)
  {
    const __bf16* aP0 = hr + (long)(mBase + wave * 32 + rloc) * 512 + cg;
    const __bf16* aP1 = aP0 + 16 * 512;
    const __bf16* bP0 = B2r + (long)e * (1024L * 512) +
                        (long)(nTile * BN + wave * 32 + rloc) * 512 + cg;
    const __bf16* bP1 = bP0 + 16 * 512;
    for (int k0 = 0; k0 < 512; k0 += BK) {
      gl_lds16(aP0 + k0, lA0);
      gl_lds16(aP1 + k0, lA1);
      gl_lds16(bP0 + k0, lB0);
      gl_lds16(bP1 + k0, lB1);
      __syncthreads();
      bf16x8 af[4], bf[4];
#pragma unroll
      for (int i = 0; i < 4; ++i) af[i] = *(const bf16x8*)&As[aBase + i * 16 * BK];
#pragma unroll
      for (int j = 0; j < 4; ++j) bf[j] = *(const bf16x8*)&Bs[bBase + j * 16 * BK];
#pragma unroll
      for (int i = 0; i < 4; ++i)
#pragma unroll
        for (int j = 0; j < 4; ++j)
          acc[i][j] = __builtin_amdgcn_mfma_f32_16x16x32_bf16(af[i], bf[j], acc[i][j], 0, 0, 0);
      __syncthreads();
    }
  }

  int q = lane >> 4, c = lane & 15;
#pragma unroll
  for (int i = 0; i < 4; ++i) {
    int rowLoc = wRow + i * 16 + q * 4;
#pragma unroll
    for (int r = 0; r < 4; ++r) {
      int tok = perm[mBase + rowLoc + r];
      if (tok >= 0) {
        float* op = out + (long)tok * 1024 + nTile * BN + wCol + c;
#pragma unroll
        for (int j = 0; j < 4; ++j) op[j * 16] = acc[i][j][r];
      }
    }
  }
}

// ---------------- launch ----------------
extern "C" void kernel_launch(void* const* d_in, const int* in_sizes, int n_in,
                              void* d_out, int out_size, void* d_ws, size_t ws_size,
                              hipStream_t stream) {
  const float* x = (const float*)d_in[0];
  const int* tok = (const int*)d_in[1];
  const float* gate_w = (const float*)d_in[2];
  const float* up_w = (const float*)d_in[3];
  const float* down_w = (const float*)d_in[4];
  const float* sgw = (const float*)d_in[5];
  const float* suw = (const float*)d_in[6];
  const float* sdw = (const float*)d_in[7];
  float* out = (float*)d_out;

  char* ws = (char*)d_ws;
  size_t off = 0;
  auto alloc = [&](size_t bytes) {
    void* p = ws + off;
    off = (off + bytes + 255) & ~(size_t)255;
    return p;
  };
  int* ctrl = (int*)alloc(1024);  // numTiles[1] tileExpert[136]
  int* numTiles = ctrl;
  int* tileExpert = ctrl + 8;
  int* perm = (int*)alloc((size_t)MPAD * 4);
  __bf16* xp = (__bf16*)alloc((size_t)MPAD * HDIM * 2);
  __bf16* B1r = (__bf16*)alloc((size_t)NEXPERTS * 1024 * 1024 * 2);  // gate|up interleaved
  __bf16* B2r = (__bf16*)alloc((size_t)NEXPERTS * 1024 * 512 * 2);
  __bf16* B1s = (__bf16*)alloc((size_t)2048 * 1024 * 2);
  __bf16* B2s = (__bf16*)alloc((size_t)1024 * 1024 * 2);
  __bf16* hs = (__bf16*)alloc((size_t)MPAD * 1024 * 2);
  __bf16* hr = (__bf16*)alloc((size_t)MPAD * 512 * 2);
  (void)ws_size;  // ~121 MB used

  // 5 dispatches total (R4; was 11)
  k_route<<<1, 1024, 0, stream>>>(tok, perm, tileExpert, numTiles);
  k_convperm<<<MPAD / 4, 256, 0, stream>>>(x, perm, xp);
  k_trans<<<3840, 256, 0, stream>>>(gate_w, up_w, down_w, sgw, suw, sdw, B1r, B2r, B1s, B2s);
  k_up<<<dim3(MAX_TILES, 24), 256, 0, stream>>>(xp, B1s, B1r, hs, hr, tileExpert, numTiles);
  k_down<<<dim3(MAX_TILES, 8), 256, 0, stream>>>(hs, hr, B2s, B2r, out, perm, tileExpert,
                                                 numTiles);
}

// Round 5
// 440.921 us; speedup vs baseline: 1.3762x; 1.0161x over previous
//
#include <hip/hip_runtime.h>
#include <cstdint>

#define N_TOK 16384
#define HDIM 1024
#define NEXPERTS 8
#define VOCABM1 50256
#define BM 128
#define BN 128
#define BK 32
#define MAX_TILES 136          // 16384/128 + 8 (worst-case padding); 136 = 17*8
#define MPAD (MAX_TILES * BM)  // 17408

typedef __attribute__((ext_vector_type(8))) __bf16 bf16x8;
typedef __attribute__((ext_vector_type(4))) __bf16 bf16x4;
typedef __attribute__((ext_vector_type(2))) __bf16 bf16x2;
typedef __attribute__((ext_vector_type(4))) float f32x4;

__device__ inline void gl_lds16(const void* g, void* l) {
  __builtin_amdgcn_global_load_lds(
      (const __attribute__((address_space(1))) void*)g,
      (__attribute__((address_space(3))) void*)l, 16, 0, 0);
}

__device__ inline int expert_of(int t) {
  t = t < 0 ? 0 : (t > VOCABM1 ? VOCABM1 : t);
  return t & 7;
}

// ---------------- fused routing: histogram + tile table + padded permutation ----------------
__global__ __launch_bounds__(1024) void k_route(const int* __restrict__ tok,
                                                int* __restrict__ perm,
                                                int* __restrict__ tileExpert,
                                                int* __restrict__ numTiles) {
  __shared__ int cnt[NEXPERTS];
  __shared__ int cur[NEXPERTS];
  int tid = threadIdx.x;
  if (tid < NEXPERTS) cnt[tid] = 0;
  __syncthreads();

  int base = tid * 16;
  int4 v[4];
  const int4* t4 = (const int4*)(tok + base);
#pragma unroll
  for (int i = 0; i < 4; ++i) v[i] = t4[i];
  int myE[16];
  int loc[NEXPERTS];
#pragma unroll
  for (int e = 0; e < NEXPERTS; ++e) loc[e] = 0;
#pragma unroll
  for (int i = 0; i < 16; ++i) {
    int e = expert_of(((const int*)v)[i]);
    myE[i] = e;
    ++loc[e];
  }
#pragma unroll
  for (int e = 0; e < NEXPERTS; ++e)
    if (loc[e]) atomicAdd(&cnt[e], loc[e]);
  __syncthreads();

  if (tid == 0) {
    int t = 0;
    for (int e = 0; e < NEXPERTS; ++e) {
      cur[e] = t * BM;  // padded offset doubles as scatter cursor
      int nt = (cnt[e] + BM - 1) / BM;
      for (int i = 0; i < nt; ++i) tileExpert[t++] = e;
    }
    *numTiles = t;
  }
  __syncthreads();

  for (int i = tid; i < MPAD; i += 1024) perm[i] = -1;
  __syncthreads();

#pragma unroll
  for (int i = 0; i < 16; ++i) {
    int pos = atomicAdd(&cur[myE[i]], 1);
    perm[pos] = base + i;
  }
}

// ---------------- merged prep: weight transpose+convert AND x gather+convert (R5) ----------------
// blocks [0,3840): 64x64 weight transpose tiles. blocks [3840,8192): xp[p]=bf16(x[perm[p]]).
__global__ void k_prep(const float* __restrict__ gw, const float* __restrict__ uw,
                       const float* __restrict__ dw, const float* __restrict__ sgw,
                       const float* __restrict__ suw, const float* __restrict__ sdw,
                       __bf16* __restrict__ B1r, __bf16* __restrict__ B2r,
                       __bf16* __restrict__ B1s, __bf16* __restrict__ B2s,
                       const float* __restrict__ x, const int* __restrict__ perm,
                       __bf16* __restrict__ xp) {
  int b = blockIdx.x;
  if (b >= 3840) {  // ---- gather-convert part ----
    int tid = threadIdx.x;
    int p = (b - 3840) * 4 + (tid >> 6);
    int t = perm[p];
    __bf16* dst = xp + (long)p * HDIM;
    int c0 = (tid & 63) * 4;
    if (t < 0) {
      bf16x4 z = {};
#pragma unroll
      for (int it = 0; it < 4; ++it) *(bf16x4*)(dst + c0 + it * 256) = z;
    } else {
      const float* src = x + (long)t * HDIM;
#pragma unroll
      for (int it = 0; it < 4; ++it) {
        float4 v = *(const float4*)(src + c0 + it * 256);
        bf16x4 o = {(__bf16)v.x, (__bf16)v.y, (__bf16)v.z, (__bf16)v.w};
        *(bf16x4*)(dst + c0 + it * 256) = o;
      }
    }
    return;
  }
  // ---- transpose part: src [K][N] fp32 -> dst [rowmap(n)][K] bf16 ----
  const float* src;
  __bf16* dst;
  int K, N, interleave, slot, xt, yt;
  if (b < 2048) {  // gate_w/up_w -> B1r (16-col gate/up interleave)
    slot = b >> 10;
    int r = b & 1023, e = r >> 7, t = r & 127;
    xt = t & 7; yt = t >> 3;
    K = 1024; N = 512; interleave = 1;
    src = (slot ? uw : gw) + (long)e * (1024L * 512);
    dst = B1r + (long)e * (1024L * 1024);
  } else if (b < 3072) {  // down_w -> B2r
    int r = b - 2048, e = r >> 7, t = r & 127;
    xt = t & 15; yt = t >> 4;
    K = 512; N = 1024; interleave = 0; slot = 0;
    src = dw + (long)e * (512L * 1024);
    dst = B2r + (long)e * (1024L * 512);
  } else if (b < 3584) {  // shared gate/up -> B1s
    int r = b - 3072;
    slot = r >> 8;
    int t = r & 255;
    xt = t & 15; yt = t >> 4;
    K = 1024; N = 1024; interleave = 1;
    src = slot ? suw : sgw;
    dst = B1s;
  } else {  // shared down -> B2s
    int t = b - 3584;
    xt = t & 15; yt = t >> 4;
    K = 1024; N = 1024; interleave = 0; slot = 0;
    src = sdw;
    dst = B2s;
  }

  __shared__ float tile[64][65];
  int n0 = xt * 64, k0 = yt * 64;
  int tid = threadIdx.x, tx = tid & 15, ty = tid >> 4;
#pragma unroll
  for (int rr = 0; rr < 64; rr += 16) {
    float4 v = *(const float4*)(src + (long)(k0 + ty + rr) * N + n0 + tx * 4);
    tile[ty + rr][tx * 4 + 0] = v.x;
    tile[ty + rr][tx * 4 + 1] = v.y;
    tile[ty + rr][tx * 4 + 2] = v.z;
    tile[ty + rr][tx * 4 + 3] = v.w;
  }
  __syncthreads();
  int kp = tid & 31, rs = tid >> 5;
#pragma unroll
  for (int rr = 0; rr < 64; rr += 8) {
    int n = n0 + rs + rr;
    int row = interleave ? (((n >> 4) << 5) | (slot << 4) | (n & 15)) : n;
    bf16x2 u = {(__bf16)tile[2 * kp][rs + rr], (__bf16)tile[2 * kp + 1][rs + rr]};
    *(bf16x2*)(dst + (long)row * K + k0 + 2 * kp) = u;
  }
}

// ---------------- fused up-projection GEMM (shared + routed) ----------------
// A = xp [MPAD][1024]. ny<16: B=B1s (shared), out hs; ny>=16: B=B1r[e], out hr.
// R5: flat grid + XCD swizzle. xcd = g%8 (round-robin heuristic); consecutive ids on
// one XCD are consecutive ny of the SAME mTile -> the co-resident ~75 blocks/XCD share
// ~3 A-slices (<1MB) in that XCD's private L2 instead of thrashing L3.
__global__ __launch_bounds__(256) void k_up(
    const __bf16* __restrict__ A, const __bf16* __restrict__ B1s,
    const __bf16* __restrict__ B1r, __bf16* __restrict__ hs, __bf16* __restrict__ hr,
    const int* __restrict__ tileExpert, const int* __restrict__ numTiles) {
  int g = blockIdx.x;
  int s = g >> 3;
  int mTile = (s / 24) * 8 + (g & 7);
  int ny = s % 24;
  if (mTile >= *numTiles) return;
  bool sh = (ny < 16);
  const __bf16* Bb = sh ? (B1s + (long)ny * BN * 1024)
                        : (B1r + (long)tileExpert[mTile] * (1024L * 1024) +
                           (long)(ny - 16) * BN * 1024);

  __shared__ __bf16 As[BM * BK];
  __shared__ __bf16 Bs[BN * BK];

  int tid = threadIdx.x, lane = tid & 63, wave = tid >> 6;
  int wRow = (wave >> 1) * 64, wCol = (wave & 1) * 64;
  int mBase = mTile * BM;

  int rloc = lane >> 2;
  int cg = ((lane & 3) ^ ((lane >> 3) & 3)) * 8;  // swizzled global chunk (elements)
  const __bf16* aP0 = A + (long)(mBase + wave * 32 + rloc) * 1024 + cg;
  const __bf16* aP1 = aP0 + 16 * 1024;
  const __bf16* bP0 = Bb + (long)(wave * 32 + rloc) * 1024 + cg;
  const __bf16* bP1 = bP0 + 16 * 1024;
  __bf16* lA0 = &As[(wave * 32) * BK];
  __bf16* lA1 = &As[(wave * 32 + 16) * BK];
  __bf16* lB0 = &Bs[(wave * 32) * BK];
  __bf16* lB1 = &Bs[(wave * 32 + 16) * BK];

  int m = lane & 15;
  int qs = ((lane >> 4) ^ ((lane >> 1) & 3)) * 8;  // swizzled read chunk (elements)
  const int aBase = (wRow + m) * BK + qs;
  const int bBase = (wCol + m) * BK + qs;

  f32x4 acc[4][4] = {};
  for (int k0 = 0; k0 < 1024; k0 += BK) {
    gl_lds16(aP0 + k0, lA0);
    gl_lds16(aP1 + k0, lA1);
    gl_lds16(bP0 + k0, lB0);
    gl_lds16(bP1 + k0, lB1);
    __syncthreads();
    bf16x8 af[4], bf[4];
#pragma unroll
    for (int i = 0; i < 4; ++i) af[i] = *(const bf16x8*)&As[aBase + i * 16 * BK];
#pragma unroll
    for (int j = 0; j < 4; ++j) bf[j] = *(const bf16x8*)&Bs[bBase + j * 16 * BK];
#pragma unroll
    for (int i = 0; i < 4; ++i)
#pragma unroll
      for (int j = 0; j < 4; ++j)
        acc[i][j] = __builtin_amdgcn_mfma_f32_16x16x32_bf16(af[i], bf[j], acc[i][j], 0, 0, 0);
    __syncthreads();
  }

  int q = lane >> 4, c = lane & 15;  // C/D: col = lane&15, row = q*4 + reg
  __bf16* dst = sh ? hs : hr;
  int ldh = sh ? 1024 : 512;
  int hColBase = (sh ? ny * 64 : (ny - 16) * 64) + (wCol >> 1);
#pragma unroll
  for (int i = 0; i < 4; ++i) {
    int rBase = mBase + wRow + i * 16 + q * 4;
#pragma unroll
    for (int jp = 0; jp < 2; ++jp) {
      f32x4 g2 = acc[i][2 * jp], u = acc[i][2 * jp + 1];
#pragma unroll
      for (int r = 0; r < 4; ++r) {
        float gv = g2[r];
        float sv = gv / (1.f + __expf(-gv)) * u[r];
        dst[(long)(rBase + r) * ldh + hColBase + jp * 16 + c] = (__bf16)sv;
      }
    }
  }
}

// ---------------- fused down-projection GEMM: out[perm[p]] = hs[p]*B2s + hr[p]*B2r[e] ----------------
__global__ __launch_bounds__(256) void k_down(
    const __bf16* __restrict__ hs, const __bf16* __restrict__ hr,
    const __bf16* __restrict__ B2s, const __bf16* __restrict__ B2r,
    float* __restrict__ out, const int* __restrict__ perm,
    const int* __restrict__ tileExpert, const int* __restrict__ numTiles) {
  int g = blockIdx.x;  // R5: XCD swizzle (see k_up)
  int s = g >> 3;
  int mTile = (s / 8) * 8 + (g & 7);
  int nTile = s % 8;
  if (mTile >= *numTiles) return;
  int e = tileExpert[mTile];

  __shared__ __bf16 As[BM * BK];
  __shared__ __bf16 Bs[BN * BK];

  int tid = threadIdx.x, lane = tid & 63, wave = tid >> 6;
  int wRow = (wave >> 1) * 64, wCol = (wave & 1) * 64;
  int mBase = mTile * BM;

  int rloc = lane >> 2;
  int cg = ((lane & 3) ^ ((lane >> 3) & 3)) * 8;
  __bf16* lA0 = &As[(wave * 32) * BK];
  __bf16* lA1 = &As[(wave * 32 + 16) * BK];
  __bf16* lB0 = &Bs[(wave * 32) * BK];
  __bf16* lB1 = &Bs[(wave * 32 + 16) * BK];

  int m = lane & 15;
  int qs = ((lane >> 4) ^ ((lane >> 1) & 3)) * 8;
  const int aBase = (wRow + m) * BK + qs;
  const int bBase = (wCol + m) * BK + qs;

  f32x4 acc[4][4] = {};

  // phase 1: shared down (K=1024)
  {
    const __bf16* aP0 = hs + (long)(mBase + wave * 32 + rloc) * 1024 + cg;
    const __bf16* aP1 = aP0 + 16 * 1024;
    const __bf16* bP0 = B2s + (long)(nTile * BN + wave * 32 + rloc) * 1024 + cg;
    const __bf16* bP1 = bP0 + 16 * 1024;
    for (int k0 = 0; k0 < 1024; k0 += BK) {
      gl_lds16(aP0 + k0, lA0);
      gl_lds16(aP1 + k0, lA1);
      gl_lds16(bP0 + k0, lB0);
      gl_lds16(bP1 + k0, lB1);
      __syncthreads();
      bf16x8 af[4], bf[4];
#pragma unroll
      for (int i = 0; i < 4; ++i) af[i] = *(const bf16x8*)&As[aBase + i * 16 * BK];
#pragma unroll
      for (int j = 0; j < 4; ++j) bf[j] = *(const bf16x8*)&Bs[bBase + j * 16 * BK];
#pragma unroll
      for (int i = 0; i < 4; ++i)
#pragma unroll
        for (int j = 0; j < 4; ++j)
          acc[i][j] = __builtin_amdgcn_mfma_f32_16x16x32_bf16(af[i], bf[j], acc[i][j], 0, 0, 0);
      __syncthreads();
    }
  }
  // phase 2: routed down (K=512)
  {
    const __bf16* aP0 = hr + (long)(mBase + wave * 32 + rloc) * 512 + cg;
    const __bf16* aP1 = aP0 + 16 * 512;
    const __bf16* bP0 = B2r + (long)e * (1024L * 512) +
                        (long)(nTile * BN + wave * 32 + rloc) * 512 + cg;
    const __bf16* bP1 = bP0 + 16 * 512;
    for (int k0 = 0; k0 < 512; k0 += BK) {
      gl_lds16(aP0 + k0, lA0);
      gl_lds16(aP1 + k0, lA1);
      gl_lds16(bP0 + k0, lB0);
      gl_lds16(bP1 + k0, lB1);
      __syncthreads();
      bf16x8 af[4], bf[4];
#pragma unroll
      for (int i = 0; i < 4; ++i) af[i] = *(const bf16x8*)&As[aBase + i * 16 * BK];
#pragma unroll
      for (int j = 0; j < 4; ++j) bf[j] = *(const bf16x8*)&Bs[bBase + j * 16 * BK];
#pragma unroll
      for (int i = 0; i < 4; ++i)
#pragma unroll
        for (int j = 0; j < 4; ++j)
          acc[i][j] = __builtin_amdgcn_mfma_f32_16x16x32_bf16(af[i], bf[j], acc[i][j], 0, 0, 0);
      __syncthreads();
    }
  }

  int q = lane >> 4, c = lane & 15;
#pragma unroll
  for (int i = 0; i < 4; ++i) {
    int rowLoc = wRow + i * 16 + q * 4;
#pragma unroll
    for (int r = 0; r < 4; ++r) {
      int tok = perm[mBase + rowLoc + r];
      if (tok >= 0) {
        float* op = out + (long)tok * 1024 + nTile * BN + wCol + c;
#pragma unroll
        for (int j = 0; j < 4; ++j) op[j * 16] = acc[i][j][r];
      }
    }
  }
}

// ---------------- launch ----------------
extern "C" void kernel_launch(void* const* d_in, const int* in_sizes, int n_in,
                              void* d_out, int out_size, void* d_ws, size_t ws_size,
                              hipStream_t stream) {
  const float* x = (const float*)d_in[0];
  const int* tok = (const int*)d_in[1];
  const float* gate_w = (const float*)d_in[2];
  const float* up_w = (const float*)d_in[3];
  const float* down_w = (const float*)d_in[4];
  const float* sgw = (const float*)d_in[5];
  const float* suw = (const float*)d_in[6];
  const float* sdw = (const float*)d_in[7];
  float* out = (float*)d_out;

  char* ws = (char*)d_ws;
  size_t off = 0;
  auto alloc = [&](size_t bytes) {
    void* p = ws + off;
    off = (off + bytes + 255) & ~(size_t)255;
    return p;
  };
  int* ctrl = (int*)alloc(1024);  // numTiles[1] tileExpert[136]
  int* numTiles = ctrl;
  int* tileExpert = ctrl + 8;
  int* perm = (int*)alloc((size_t)MPAD * 4);
  __bf16* xp = (__bf16*)alloc((size_t)MPAD * HDIM * 2);
  __bf16* B1r = (__bf16*)alloc((size_t)NEXPERTS * 1024 * 1024 * 2);  // gate|up interleaved
  __bf16* B2r = (__bf16*)alloc((size_t)NEXPERTS * 1024 * 512 * 2);
  __bf16* B1s = (__bf16*)alloc((size_t)2048 * 1024 * 2);
  __bf16* B2s = (__bf16*)alloc((size_t)1024 * 1024 * 2);
  __bf16* hs = (__bf16*)alloc((size_t)MPAD * 1024 * 2);
  __bf16* hr = (__bf16*)alloc((size_t)MPAD * 512 * 2);
  (void)ws_size;  // ~121 MB used

  // 4 dispatches total (R5; was 5)
  k_route<<<1, 1024, 0, stream>>>(tok, perm, tileExpert, numTiles);
  k_prep<<<3840 + MPAD / 4, 256, 0, stream>>>(gate_w, up_w, down_w, sgw, suw, sdw, B1r, B2r,
                                              B1s, B2s, x, perm, xp);
  k_up<<<MAX_TILES * 24, 256, 0, stream>>>(xp, B1s, B1r, hs, hr, tileExpert, numTiles);
  k_down<<<MAX_TILES * 8, 256, 0, stream>>>(hs, hr, B2s, B2r, out, perm, tileExpert,
                                            numTiles);
}